// Round 8
// baseline (1298.537 us; speedup 1.0000x reference)
//
#include <hip/hip_runtime.h>
#include <math.h>

// Problem constants (from reference)
constexpr int Mdim = 8192;
constexpr int Wdim = 100;
constexpr int Kdim = 6;
constexpr int Ddim = 300;
constexpr int Rtop = 25;
constexpr int Hdim = 100;

// Output layout: x [M,K], beta [M,W], sim [M,K] concatenated flat
constexpr int XOFF = 0;
constexpr int BOFF = Mdim * Kdim;              // 49152
constexpr int SOFF = BOFF + Mdim * Wdim;       // 868352

// launch_bounds(256,4): cap VGPR at 128 -> 4 blocks/CU (16 waves/CU).
// Persistent per-thread state in phase 2 is ~100 VGPRs (48 acc + 32 prefetch
// + addressing), so 128 is safe; LDS (~23.5 KB) permits 6 blocks/CU.
// If the first bench shows scratch/spills, revert to (256,3).
extern "C" __global__ void __launch_bounds__(256, 4)
fused_entity_scorer(const float* __restrict__ ctxt,   // [M,W,D]
                    const float* __restrict__ cand,   // [M,K,D]
                    const float* __restrict__ pem,    // [M,K]
                    const float* __restrict__ Av,     // [D]
                    const float* __restrict__ Bv,     // [D]
                    const float* __restrict__ W1,     // [H,2]
                    const float* __restrict__ b1,     // [H]
                    const float* __restrict__ W2,     // [1,H]
                    const float* __restrict__ b2,     // [1]
                    float* __restrict__ out)
{
    __shared__ float sA[Ddim];
    __shared__ float sB[Ddim];
    __shared__ float sCandA[Kdim * Ddim];   // cand * A (7.2 KB)
    __shared__ float sCandB[Kdim * Ddim];   // cand * B (7.2 KB)
    __shared__ float sS[Kdim * Wdim];       // scores s[k][w]
    __shared__ float sT[Kdim * Wdim];       // t[k][w] = cand_k . (B*ctxt_w)
    __shared__ float sU[Wdim];
    __shared__ float sE[Wdim];              // masked -> exp -> beta
    __shared__ float sW1[2 * Hdim];
    __shared__ float sB1[Hdim];
    __shared__ float sW2[Hdim];
    __shared__ float sScal[4];              // [0]=top_min [1]=rowmax [2]=sum [3]=b2

    const int m = blockIdx.x;
    const int t = threadIdx.x;

    // ---------------- Phase 0: stage small weights ----------------
    for (int i = t; i < Ddim; i += 256) { sA[i] = Av[i]; sB[i] = Bv[i]; }
    for (int i = t; i < 2 * Hdim; i += 256) sW1[i] = W1[i];
    if (t < Hdim) { sB1[t] = b1[t]; sW2[t] = W2[t]; }
    if (t == 0) sScal[3] = b2[0];
    __syncthreads();

    // ---------------- Phase 1: stage A/B-scaled candidates ----------------
    const float* candm = cand + (size_t)m * (Kdim * Ddim);
    for (int i = t; i < Kdim * Ddim; i += 256) {
        const int d = i % Ddim;
        const float c = candm[i];
        sCandA[i] = c * sA[d];
        sCandB[i] = c * sB[d];
    }
    __syncthreads();

    // ---------------- Phase 2: single pass over ctxt ----------------
    // 200 active threads: g = w-group (4 rows), ds = d-split (8 x float4 chunks)
    if (t < 200) {
        float accS[Kdim][4];
        float accT[Kdim][4];
#pragma unroll
        for (int k = 0; k < Kdim; ++k)
#pragma unroll
            for (int j = 0; j < 4; ++j) { accS[k][j] = 0.f; accT[k][j] = 0.f; }

        const int g  = t >> 3;   // 0..24  (w-group: rows 4g..4g+3)
        const int ds = t & 7;    // 0..7   (d-split: float4 chunks c = ds mod 8)
        const float* cb = ctxt + (size_t)m * (Wdim * Ddim) + (size_t)(g * 4) * Ddim;
        const int nch = (ds < 3) ? 10 : 9;   // chunks c = ds + 8*i, c < 75

        float4 cur[4];
#pragma unroll
        for (int j = 0; j < 4; ++j)
            cur[j] = *(const float4*)(cb + j * Ddim + 4 * ds);

        for (int i = 0; i < nch; ++i) {
            const int c  = ds + 8 * i;
            const int cn = (i + 1 < nch) ? (c + 8) : c;   // clamp: dummy reload on last iter
            float4 nxt[4];
#pragma unroll
            for (int j = 0; j < 4; ++j)
                nxt[j] = *(const float4*)(cb + j * Ddim + 4 * cn);

#pragma unroll
            for (int k = 0; k < Kdim; ++k) {
                const float4 a4 = *(const float4*)(&sCandA[k * Ddim + 4 * c]);
                const float4 b4 = *(const float4*)(&sCandB[k * Ddim + 4 * c]);
#pragma unroll
                for (int j = 0; j < 4; ++j) {
                    accS[k][j] = fmaf(a4.x, cur[j].x, accS[k][j]);
                    accS[k][j] = fmaf(a4.y, cur[j].y, accS[k][j]);
                    accS[k][j] = fmaf(a4.z, cur[j].z, accS[k][j]);
                    accS[k][j] = fmaf(a4.w, cur[j].w, accS[k][j]);
                    accT[k][j] = fmaf(b4.x, cur[j].x, accT[k][j]);
                    accT[k][j] = fmaf(b4.y, cur[j].y, accT[k][j]);
                    accT[k][j] = fmaf(b4.z, cur[j].z, accT[k][j]);
                    accT[k][j] = fmaf(b4.w, cur[j].w, accT[k][j]);
                }
            }
#pragma unroll
            for (int j = 0; j < 4; ++j) cur[j] = nxt[j];
        }

        // ---- d-split reduction via wave shuffle (xor 1,2,4 stays inside the
        // 8-lane ds-group; threads 192..199 are lanes 0..7 of wave 3 -> safe).
        // Lane with ds==k writes row k for this thread-group's 4 w's.
#pragma unroll
        for (int k = 0; k < Kdim; ++k) {
#pragma unroll
            for (int j = 0; j < 4; ++j) {
                float s  = accS[k][j];
                float tt = accT[k][j];
                s  += __shfl_xor(s, 1, 64);
                s  += __shfl_xor(s, 2, 64);
                s  += __shfl_xor(s, 4, 64);
                tt += __shfl_xor(tt, 1, 64);
                tt += __shfl_xor(tt, 2, 64);
                tt += __shfl_xor(tt, 4, 64);
                if (ds == k) {
                    sS[k * 100 + 4 * g + j] = s;
                    sT[k * 100 + 4 * g + j] = tt;
                }
            }
        }
    }
    __syncthreads();

    // ---------------- Phase 4: u = max_k s ----------------
    if (t < Wdim) {
        float mx = sS[t];
#pragma unroll
        for (int k = 1; k < Kdim; ++k) mx = fmaxf(mx, sS[k * 100 + t]);
        sU[t] = mx;
    }
    __syncthreads();

    // ---------------- Phase 5: top-R threshold (lex-rank; exact top_k semantics) ----------------
    if (t < Wdim) {
        const float uw = sU[t];
        int cnt = 0;
        for (int j = 0; j < Wdim; ++j) {
            const float uj = sU[j];
            cnt += (uj > uw) || (uj == uw && j < t);
        }
        if (cnt == Rtop - 1) sScal[0] = uw;   // exactly one thread (strict total order)
    }
    __syncthreads();

    // masked values
    const float topmin = sScal[0];
    if (t < Wdim) {
        const float uw = sU[t];
        sE[t] = (uw - topmin > 0.0f) ? uw : (topmin - 50.0f);
    }
    __syncthreads();

    // row max (softmax stabilization)
    if (t < 64) {
        float v = sE[t];
        if (t + 64 < Wdim) v = fmaxf(v, sE[t + 64]);
#pragma unroll
        for (int o = 32; o > 0; o >>= 1) v = fmaxf(v, __shfl_xor(v, o, 64));
        if (t == 0) sScal[1] = v;
    }
    __syncthreads();

    const float rowmax = sScal[1];
    if (t < Wdim) sE[t] = expf(sE[t] - rowmax);
    __syncthreads();

    if (t < 64) {
        float v = sE[t] + ((t + 64 < Wdim) ? sE[t + 64] : 0.f);
#pragma unroll
        for (int o = 32; o > 0; o >>= 1) v += __shfl_xor(v, o, 64);
        if (t == 0) sScal[2] = v;
    }
    __syncthreads();

    const float denom = sScal[2];
    if (t < Wdim) {
        const float b = sE[t] / denom;
        sE[t] = b;                                   // beta
        out[BOFF + (size_t)m * Wdim + t] = b;
    }
    __syncthreads();

    // ---------------- Phase 6: sim_k = sum_w beta_w * t[k][w]; then MLP ----------------
    if (t < 192) {
        const int k = t >> 5;        // 0..5
        const int j = t & 31;        // lane in 32-group
        float acc = 0.f;
        for (int w = j; w < Wdim; w += 32)
            acc = fmaf(sE[w], sT[k * 100 + w], acc);
#pragma unroll
        for (int o = 16; o > 0; o >>= 1) acc += __shfl_xor(acc, o, 64);
        // all 32 lanes of the k-group now hold sim_k
        if (j == 0) out[SOFF + (size_t)m * Kdim + k] = acc;
        const float simk = acc;

        // tiny MLP: x = sum_h relu(sim*W1[h,0] + p*W1[h,1] + b1[h]) * W2[h] + b2
        const float p = pem[(size_t)m * Kdim + k];
        float acc2 = 0.f;
        for (int h = j; h < Hdim; h += 32) {
            float hv = fmaf(simk, sW1[2 * h], fmaf(p, sW1[2 * h + 1], sB1[h]));
            hv = fmaxf(hv, 0.f);
            acc2 = fmaf(hv, sW2[h], acc2);
        }
#pragma unroll
        for (int o = 16; o > 0; o >>= 1) acc2 += __shfl_xor(acc2, o, 64);
        if (j == 0) out[XOFF + (size_t)m * Kdim + k] = acc2 + sScal[3];
    }
}

extern "C" void kernel_launch(void* const* d_in, const int* in_sizes, int n_in,
                              void* d_out, int out_size, void* d_ws, size_t ws_size,
                              hipStream_t stream) {
    const float* ctxt = (const float*)d_in[0];
    const float* cand = (const float*)d_in[1];
    const float* pem  = (const float*)d_in[2];
    const float* Av   = (const float*)d_in[3];
    const float* Bv   = (const float*)d_in[4];
    const float* W1   = (const float*)d_in[5];
    const float* b1   = (const float*)d_in[6];
    const float* W2   = (const float*)d_in[7];
    const float* b2   = (const float*)d_in[8];
    float* out = (float*)d_out;

    hipLaunchKernelGGL(fused_entity_scorer, dim3(Mdim), dim3(256), 0, stream,
                       ctxt, cand, pem, Av, Bv, W1, b1, W2, b2, out);
}